// Round 8
// baseline (227.873 us; speedup 1.0000x reference)
//
#include <hip/hip_runtime.h>
#include <stdint.h>

#define BB 16
#define SS 10
#define CLSN 4
#define FGN 3
#define HH 192
#define WW 192
#define NPIX (HH * WW)    // 36864
#define WPR 3             // u64 words per row
#define NWORDS (HH * WPR) // 576
#define NPAIR (BB * SS)   // 160
#define NTASK (NPAIR * FGN) // 480
#define NT 256
#define NW 4
#define MAXR 80           // max runs per row (mean ~36, sigma ~5 -> 8.5 sigma margin)

typedef unsigned long long u64;
typedef unsigned short u16;
typedef unsigned int u32;

// Dynamic LDS layout (bytes):
//   fgw   : 0      .. 4608      (576 u64)
//   cmp   : 4608   .. 9216      (576 u64)
//   parent: 9216   .. 70656     (15360 u32)
//   wlist : 70656  .. 71808     (576 short)
//   wkey  : 71808  .. 71824     (4 u32)
//   wsum  : 71824  .. 71856     (4 double)
//   misc  : 71856  .. 71872     (seedSh, cntSh, seedRunSh)
#define SMEM_BYTES 71872

// full adder: s = a^b^c, cy = majority(a,b,c)
#define FAD(a, b, c, s, cy)            \
    do {                               \
        u64 t_ = (a) ^ (b);            \
        (s) = t_ ^ (c);                \
        (cy) = ((a) & (b)) | (t_ & (c)); \
    } while (0)

// bit-sliced 3x3 ones-conv of bitboard `bd` at word k: 4 count bit-planes + center
__device__ __forceinline__ void plane9(const u64* bd, int k,
                                       u64& P0, u64& P1, u64& P2, u64& P3, u64& mid)
{
    const int r = k / WPR;
    const int wc = k - r * WPR;
    u64 rows[3][3];
#pragma unroll
    for (int di = 0; di < 3; ++di) {
        int rr = r + di - 1;
#pragma unroll
        for (int dj = 0; dj < 3; ++dj) {
            int ww = wc + dj - 1;
            rows[di][dj] = (rr >= 0 && rr < HH && ww >= 0 && ww < WPR)
                           ? bd[rr * WPR + ww] : 0ULL;
        }
    }
    mid = rows[1][1];
    u64 in[9];
#pragma unroll
    for (int i = 0; i < 3; ++i) {
        u64 m = rows[i][1], lf = rows[i][0], rg = rows[i][2];
        in[3 * i + 0] = m;
        in[3 * i + 1] = (m << 1) | (lf >> 63);
        in[3 * i + 2] = (m >> 1) | (rg << 63);
    }
    u64 s0a, c0a, s0b, c0b, s0c, c0c, c0d, s1a, c1a, c1b;
    FAD(in[0], in[1], in[2], s0a, c0a);
    FAD(in[3], in[4], in[5], s0b, c0b);
    FAD(in[6], in[7], in[8], s0c, c0c);
    FAD(s0a, s0b, s0c, P0, c0d);
    FAD(c0a, c0b, c0c, s1a, c1a);
    P1 = s1a ^ c0d;
    c1b = s1a & c0d;
    P2 = c1a ^ c1b;
    P3 = c1a & c1b;
}

// streaming maximal-run extraction over a 3-u64 row (192 bits).
// pos: scan cursor (in/out). Returns run [s,e] or false.
__device__ __forceinline__ bool nextRun(const u64* a, int& pos, int& s, int& e)
{
    if (pos >= 192) return false;
    int wi = pos >> 6, bi = pos & 63;
    u64 m = a[wi] & (~0ULL << bi);
    while (!m) {
        if (++wi >= 3) { pos = 192; return false; }
        m = a[wi];
    }
    s = (wi << 6) + (int)(__ffsll(m) - 1);
    int wj = s >> 6, bj = s & 63;
    u64 n = (~a[wj]) & (bj == 63 ? 0ULL : (~0ULL << (bj + 1)));
    while (!n) {
        if (++wj >= 3) { e = 191; pos = 192; return true; }
        n = ~a[wj];
    }
    const int q = (wj << 6) + (int)(__ffsll(n) - 1);  // first clear > s
    e = q - 1;
    pos = q + 1;
    return true;
}

// lock-free min-union on LDS parent array
__device__ __forceinline__ void uf_union(u32* parent, u32 a, u32 b)
{
    while (true) {
        while (parent[a] != a) a = parent[a];
        while (parent[b] != b) b = parent[b];
        if (a == b) return;
        u32 hi = a > b ? a : b;
        u32 lo = a > b ? b : a;
        u32 old = atomicCAS(&parent[hi], hi, lo);
        if (old == hi) return;
        a = lo; b = old;
    }
}

__global__ __launch_bounds__(NT) void cc_fused(
    const float* __restrict__ preds,
    const int* __restrict__ samples,
    double* __restrict__ acc)
{
    extern __shared__ char smem[];
    u64* fgw        = (u64*)(smem);
    u64* cmp        = (u64*)(smem + 4608);
    u32* parent     = (u32*)(smem + 9216);
    short* wlist    = (short*)(smem + 70656);
    u32* wkey       = (u32*)(smem + 71808);
    double* wsum    = (double*)(smem + 71824);
    u32* seedShP    = (u32*)(smem + 71856);
    int* cntShP     = (int*)(smem + 71860);
    u32* seedRunP   = (u32*)(smem + 71864);

    const int blk = blockIdx.x;
    const int c = 1 + blk / NPAIR;
    const int pair = blk % NPAIR;
    const int b = pair / SS;

    const int tid  = threadIdx.x;
    const int lane = tid & 63;
    const int wv   = tid >> 6;

    const int* __restrict__ smp  = samples + (size_t)pair * NPIX;
    const float* __restrict__ pp = preds + ((size_t)b * CLSN + c) * NPIX;

    if (tid == 0) { *cntShP = 0; *seedRunP = 0xFFFFFFFFu; }

    float facc = 0.0f;

    // ---- Phase A: int4/float4 loads; 16-px mask nibble -> LDS u16 alias of fgw.
    // Fused dense term: -sum_{v==c} log(p + 1e-8).
    {
        u16* nib = (u16*)fgw;
        for (int sc = 0; sc < 9; ++sc) {
            const int ci = sc * NT + tid;
            const int px = ci << 4;
            const int4 v0 = *(const int4*)(smp + px);
            const int4 v1 = *(const int4*)(smp + px + 4);
            const int4 v2 = *(const int4*)(smp + px + 8);
            const int4 v3 = *(const int4*)(smp + px + 12);
            const float4 q0 = *(const float4*)(pp + px);
            const float4 q1 = *(const float4*)(pp + px + 4);
            const float4 q2 = *(const float4*)(pp + px + 8);
            const float4 q3 = *(const float4*)(pp + px + 12);
            unsigned m = 0u;
#define ACC1(vv, qq, sh)                                              \
            {                                                          \
                const bool hit_ = ((vv) == c);                         \
                m |= ((unsigned)hit_) << (sh);                         \
                facc -= hit_ ? __logf((qq) + 1e-8f) : 0.0f;            \
            }
            ACC1(v0.x, q0.x, 0)  ACC1(v0.y, q0.y, 1)
            ACC1(v0.z, q0.z, 2)  ACC1(v0.w, q0.w, 3)
            ACC1(v1.x, q1.x, 4)  ACC1(v1.y, q1.y, 5)
            ACC1(v1.z, q1.z, 6)  ACC1(v1.w, q1.w, 7)
            ACC1(v2.x, q2.x, 8)  ACC1(v2.y, q2.y, 9)
            ACC1(v2.z, q2.z, 10) ACC1(v2.w, q2.w, 11)
            ACC1(v3.x, q3.x, 12) ACC1(v3.y, q3.y, 13)
            ACC1(v3.z, q3.z, 14) ACC1(v3.w, q3.w, 15)
#undef ACC1
            nib[ci] = (u16)m;
        }
    }
    __syncthreads();

    // ---- Phase B: bit-sliced neighbor counts -> argmax seed (first-max tie-break) ----
    {
        unsigned bestkey = 0u;
        for (int k = tid; k < NWORDS; k += NT) {
            u64 P0, P1, P2, P3, mid;
            plane9(fgw, k, P0, P1, P2, P3, mid);
            if (mid) {
                u64 cand = mid, t;
                unsigned v = 0;
                t = cand & P3; if (t) { cand = t; v |= 8u; }
                t = cand & P2; if (t) { cand = t; v |= 4u; }
                t = cand & P1; if (t) { cand = t; v |= 2u; }
                t = cand & P0; if (t) { cand = t; v |= 1u; }
                unsigned pix = ((unsigned)k << 6) + (unsigned)(__ffsll(cand) - 1);
                unsigned key = (v << 16) | (36863u - pix);
                if (key > bestkey) bestkey = key;
            }
        }
#pragma unroll
        for (int off = 32; off > 0; off >>= 1) {
            unsigned o = (unsigned)__shfl_xor((int)bestkey, off, 64);
            if (o > bestkey) bestkey = o;
        }
        if (lane == 0) wkey[wv] = bestkey;
    }
    __syncthreads();
    if (tid == 0) {
        unsigned kk = wkey[0];
        if (wkey[1] > kk) kk = wkey[1];
        if (wkey[2] > kk) kk = wkey[2];
        if (wkey[3] > kk) kk = wkey[3];
        *seedShP = 36863u - (kk & 0xFFFFu);
    }
    __syncthreads();

    // ---- Phase C: run-based union-find (iteration-free in component shape) ----
    const unsigned seed = *seedShP;
    const int srow = (int)(seed / WW);
    const int scol = (int)(seed % WW);

    // C1: init parent for actual runs; locate seed run
    if (tid < HH) {
        const u64* A = fgw + tid * WPR;
        int pos = 0, s, e, k = 0;
        while (k < MAXR && nextRun(A, pos, s, e)) {
            const u32 id = (u32)(tid * MAXR + k);
            parent[id] = id;
            if (tid == srow && s <= scol && scol <= e) *seedRunP = id;
            ++k;
        }
    }
    __syncthreads();

    // C2: merge adjacent rows (8-connectivity) via streaming two-pointer
    if (tid < HH - 1) {
        const u64* A = fgw + tid * WPR;
        const u64* B = fgw + (tid + 1) * WPR;
        int pa = 0, pb = 0, sa, ea, sb, eb;
        int ka = 0, kb = 0;
        bool ha = nextRun(A, pa, sa, ea);
        bool hb = nextRun(B, pb, sb, eb);
        while (ha && hb && ka < MAXR && kb < MAXR) {
            if (ea + 1 < sb) { ha = nextRun(A, pa, sa, ea); ++ka; }
            else if (eb + 1 < sa) { hb = nextRun(B, pb, sb, eb); ++kb; }
            else {
                uf_union(parent, (u32)(tid * MAXR + ka), (u32)((tid + 1) * MAXR + kb));
                if (ea <= eb) { ha = nextRun(A, pa, sa, ea); ++ka; }
                else          { hb = nextRun(B, pb, sb, eb); ++kb; }
            }
        }
    }
    __syncthreads();

    // C3: paint the seed component into cmp
    if (tid < HH) {
        u64 o0 = 0, o1 = 0, o2 = 0;
        const u32 sr = *seedRunP;
        if (sr != 0xFFFFFFFFu) {
            u32 root = sr;
            while (parent[root] != root) root = parent[root];
            const u64* A = fgw + tid * WPR;
            int pos = 0, s, e, k = 0;
            while (k < MAXR && nextRun(A, pos, s, e)) {
                u32 f = (u32)(tid * MAXR + k);
                while (parent[f] != f) f = parent[f];
                if (f == root) {
#pragma unroll
                    for (int w = 0; w < 3; ++w) {
                        const int lo = w << 6;
                        int a = s - lo, bq = e - lo;
                        if (bq < 0 || a > 63) continue;
                        const int aa = a < 0 ? 0 : a;
                        const int bb = bq > 63 ? 63 : bq;
                        u64 mm = (bb == 63 ? ~0ULL : ((1ULL << (bb + 1)) - 1ULL))
                               & (~0ULL << aa);
                        if (w == 0) o0 |= mm;
                        else if (w == 1) o1 |= mm;
                        else o2 |= mm;
                    }
                }
                ++k;
            }
        }
        cmp[tid * WPR + 0] = o0;
        cmp[tid * WPR + 1] = o1;
        cmp[tid * WPR + 2] = o2;
    }
    __syncthreads();

    // ---- Phase D: compact nonempty comp words, split across waves,
    //      software-pipelined preds gather. facc += (cnt/9 + 1) * log(p).
    for (int k = tid; k < NWORDS; k += NT)
        if (cmp[k] != 0ULL) { int idx = atomicAdd(cntShP, 1); wlist[idx] = (short)k; }
    __syncthreads();
    {
        const int n = *cntShP;
        int i = wv;
        int kc = (i < n) ? (int)wlist[i] : -1;
        float pc = 0.0f;
        if (kc >= 0) pc = pp[(kc << 6) + lane];
        while (kc >= 0) {
            const int i2 = i + NW;
            const int k2 = (i2 < n) ? (int)wlist[i2] : -1;
            float p2 = 0.0f;
            if (k2 >= 0) p2 = pp[(k2 << 6) + lane];   // next load in flight
            u64 P0, P1, P2, P3, mid;
            plane9(cmp, kc, P0, P1, P2, P3, mid);
            if ((mid >> lane) & 1ULL) {
                int ct = (int)((P0 >> lane) & 1ULL)
                       | ((int)((P1 >> lane) & 1ULL) << 1)
                       | ((int)((P2 >> lane) & 1ULL) << 2)
                       | ((int)((P3 >> lane) & 1ULL) << 3);
                facc += ((float)ct * (1.0f / 9.0f) + 1.0f) * __logf(pc + 1e-8f);
            }
            i = i2; kc = k2; pc = p2;
        }
    }

    // ---- Reduce ----
#pragma unroll
    for (int off = 32; off > 0; off >>= 1)
        facc += __shfl_xor(facc, off, 64);
    if (lane == 0) wsum[wv] = (double)facc;
    __syncthreads();
    if (tid == 0)
        atomicAdd(acc, wsum[0] + wsum[1] + wsum[2] + wsum[3]);
}

__global__ void finalize_kernel(const double* __restrict__ acc, float* __restrict__ out)
{
    if (threadIdx.x == 0 && blockIdx.x == 0)
        out[0] = (float)(-acc[0] / (double)((long long)BB * SS * NPIX));
}

extern "C" void kernel_launch(void* const* d_in, const int* in_sizes, int n_in,
                              void* d_out, int out_size, void* d_ws, size_t ws_size,
                              hipStream_t stream)
{
    const float* preds   = (const float*)d_in[0];
    const int*   samples = (const int*)d_in[1];
    double* acc = (double*)d_ws;

    hipMemsetAsync(acc, 0, sizeof(double), stream);
    hipLaunchKernelGGL(cc_fused, dim3(NTASK), dim3(NT), SMEM_BYTES, stream,
                       preds, samples, acc);
    hipLaunchKernelGGL(finalize_kernel, dim3(1), dim3(64), 0, stream,
                       acc, (float*)d_out);
}

// Round 9
// 106.061 us; speedup vs baseline: 2.1485x; 2.1485x over previous
//
#include <hip/hip_runtime.h>
#include <stdint.h>

#define BB 16
#define SS 10
#define CLSN 4
#define FGN 3
#define HH 192
#define WW 192
#define NPIX (HH * WW)    // 36864
#define WPR 3             // u64 words per row
#define NWORDS (HH * WPR) // 576
#define NPAIR (BB * SS)   // 160
#define NTASK (NPAIR * FGN) // 480
#define NT 256
#define NW 4
#define MAXRUNS 8192      // mean ~6924, sigma ~76 -> 16+ sigma margin

typedef unsigned long long u64;
typedef unsigned short u16;
typedef unsigned int u32;

// Dynamic LDS layout (bytes):
//   fgw    : 0     .. 4608    (576 u64)
//   cmp    : 4608  .. 9216    (576 u64)
//   runs   : 9216  .. 41984   (8192 u32: row<<16|s<<8|e)
//   parent : 41984 .. 74752   (8192 u32)
//   roff   : 74752 .. 75524   (193 int)
#define SMEM_BYTES 75536

// full adder: s = a^b^c, cy = majority(a,b,c)
#define FAD(a, b, c, s, cy)            \
    do {                               \
        u64 t_ = (a) ^ (b);            \
        (s) = t_ ^ (c);                \
        (cy) = ((a) & (b)) | (t_ & (c)); \
    } while (0)

// bit-sliced 3x3 ones-conv of bitboard `bd` at word k: 4 count bit-planes + center
__device__ __forceinline__ void plane9(const u64* bd, int k,
                                       u64& P0, u64& P1, u64& P2, u64& P3, u64& mid)
{
    const int r = k / WPR;
    const int wc = k - r * WPR;
    u64 rows[3][3];
#pragma unroll
    for (int di = 0; di < 3; ++di) {
        int rr = r + di - 1;
#pragma unroll
        for (int dj = 0; dj < 3; ++dj) {
            int ww = wc + dj - 1;
            rows[di][dj] = (rr >= 0 && rr < HH && ww >= 0 && ww < WPR)
                           ? bd[rr * WPR + ww] : 0ULL;
        }
    }
    mid = rows[1][1];
    u64 in[9];
#pragma unroll
    for (int i = 0; i < 3; ++i) {
        u64 m = rows[i][1], lf = rows[i][0], rg = rows[i][2];
        in[3 * i + 0] = m;
        in[3 * i + 1] = (m << 1) | (lf >> 63);
        in[3 * i + 2] = (m >> 1) | (rg << 63);
    }
    u64 s0a, c0a, s0b, c0b, s0c, c0c, c0d, s1a, c1a, c1b;
    FAD(in[0], in[1], in[2], s0a, c0a);
    FAD(in[3], in[4], in[5], s0b, c0b);
    FAD(in[6], in[7], in[8], s0c, c0c);
    FAD(s0a, s0b, s0c, P0, c0d);
    FAD(c0a, c0b, c0c, s1a, c1a);
    P1 = s1a ^ c0d;
    c1b = s1a & c0d;
    P2 = c1a ^ c1b;
    P3 = c1a & c1b;
}

// run-start masks of a row: bit set & previous bit clear
__device__ __forceinline__ void rowStarts(const u64* fr, u64 st[3])
{
    st[0] = fr[0] & ~(fr[0] << 1);
    st[1] = fr[1] & ~((fr[1] << 1) | (fr[0] >> 63));
    st[2] = fr[2] & ~((fr[2] << 1) | (fr[1] >> 63));
}

// number of start bits at position <= pos (pos in [0,191])
__device__ __forceinline__ int rankLE(const u64 st[3], int pos)
{
    int cnt = 0;
#pragma unroll
    for (int w = 0; w < 3; ++w) {
        const int lo = w << 6;
        if (pos >= lo + 63) cnt += (int)__popcll(st[w]);
        else if (pos >= lo) cnt += (int)__popcll(st[w] & ((2ULL << (pos - lo)) - 1ULL));
    }
    return cnt;
}

// ECL-CC-style find with path halving (parents only decrease -> race-safe)
__device__ __forceinline__ u32 repr(u32 v, u32* P)
{
    u32 cur = ((volatile u32*)P)[v];
    if (cur != v) {
        u32 prev = v, next;
        while (cur > (next = ((volatile u32*)P)[cur])) {
            ((volatile u32*)P)[prev] = next;
            prev = cur; cur = next;
        }
    }
    return cur;
}

__device__ __forceinline__ void unite(u32 a, u32 b, u32* P)
{
    u32 x = repr(a, P), y = repr(b, P);
    while (x != y) {
        if (x < y) { u32 t = x; x = y; y = t; }   // x > y: hook x -> y
        u32 old = atomicCAS(&P[x], x, y);
        if (old == x) return;
        x = repr(old, P);
        y = repr(y, P);
    }
}

__global__ __launch_bounds__(NT) void cc_fused(
    const float* __restrict__ preds,
    const int* __restrict__ samples,
    double* __restrict__ acc)
{
    extern __shared__ char smem[];
    u64* fgw    = (u64*)(smem);
    u64* cmp    = (u64*)(smem + 4608);
    u32* runs   = (u32*)(smem + 9216);
    u32* parent = (u32*)(smem + 41984);
    int* roff   = (int*)(smem + 74752);

    __shared__ unsigned wkey[NW];
    __shared__ double wsum[NW];
    __shared__ unsigned seedSh;
    __shared__ int cntSh;
    __shared__ u32 seedRunSh;
    __shared__ short wlist[NWORDS];

    const int blk = blockIdx.x;
    const int c = 1 + blk / NPAIR;
    const int pair = blk % NPAIR;
    const int b = pair / SS;

    const int tid  = threadIdx.x;
    const int lane = tid & 63;
    const int wv   = tid >> 6;

    const int* __restrict__ smp  = samples + (size_t)pair * NPIX;
    const float* __restrict__ pp = preds + ((size_t)b * CLSN + c) * NPIX;

    if (tid == 0) { cntSh = 0; seedRunSh = 0xFFFFFFFFu; }

    float facc = 0.0f;

    // ---- Phase A: int4/float4 loads; 16-px mask nibble -> LDS u16 alias of fgw.
    // Fused dense term: -sum_{v==c} log(p + 1e-8).
    {
        u16* nib = (u16*)fgw;
        for (int sc = 0; sc < 9; ++sc) {
            const int ci = sc * NT + tid;
            const int px = ci << 4;
            const int4 v0 = *(const int4*)(smp + px);
            const int4 v1 = *(const int4*)(smp + px + 4);
            const int4 v2 = *(const int4*)(smp + px + 8);
            const int4 v3 = *(const int4*)(smp + px + 12);
            const float4 q0 = *(const float4*)(pp + px);
            const float4 q1 = *(const float4*)(pp + px + 4);
            const float4 q2 = *(const float4*)(pp + px + 8);
            const float4 q3 = *(const float4*)(pp + px + 12);
            unsigned m = 0u;
#define ACC1(vv, qq, sh)                                              \
            {                                                          \
                const bool hit_ = ((vv) == c);                         \
                m |= ((unsigned)hit_) << (sh);                         \
                facc -= hit_ ? __logf((qq) + 1e-8f) : 0.0f;            \
            }
            ACC1(v0.x, q0.x, 0)  ACC1(v0.y, q0.y, 1)
            ACC1(v0.z, q0.z, 2)  ACC1(v0.w, q0.w, 3)
            ACC1(v1.x, q1.x, 4)  ACC1(v1.y, q1.y, 5)
            ACC1(v1.z, q1.z, 6)  ACC1(v1.w, q1.w, 7)
            ACC1(v2.x, q2.x, 8)  ACC1(v2.y, q2.y, 9)
            ACC1(v2.z, q2.z, 10) ACC1(v2.w, q2.w, 11)
            ACC1(v3.x, q3.x, 12) ACC1(v3.y, q3.y, 13)
            ACC1(v3.z, q3.z, 14) ACC1(v3.w, q3.w, 15)
#undef ACC1
            nib[ci] = (u16)m;
        }
    }
    __syncthreads();

    // ---- Phase B: bit-sliced neighbor counts -> argmax seed (first-max tie-break) ----
    {
        unsigned bestkey = 0u;
        for (int k = tid; k < NWORDS; k += NT) {
            u64 P0, P1, P2, P3, mid;
            plane9(fgw, k, P0, P1, P2, P3, mid);
            if (mid) {
                u64 cand = mid, t;
                unsigned v = 0;
                t = cand & P3; if (t) { cand = t; v |= 8u; }
                t = cand & P2; if (t) { cand = t; v |= 4u; }
                t = cand & P1; if (t) { cand = t; v |= 2u; }
                t = cand & P0; if (t) { cand = t; v |= 1u; }
                unsigned pix = ((unsigned)k << 6) + (unsigned)(__ffsll(cand) - 1);
                unsigned key = (v << 16) | (36863u - pix);
                if (key > bestkey) bestkey = key;
            }
        }
#pragma unroll
        for (int off = 32; off > 0; off >>= 1) {
            unsigned o = (unsigned)__shfl_xor((int)bestkey, off, 64);
            if (o > bestkey) bestkey = o;
        }
        if (lane == 0) wkey[wv] = bestkey;
    }
    __syncthreads();
    if (tid == 0) {
        unsigned kk = wkey[0];
        if (wkey[1] > kk) kk = wkey[1];
        if (wkey[2] > kk) kk = wkey[2];
        if (wkey[3] > kk) kk = wkey[3];
        seedSh = 36863u - (kk & 0xFFFFu);
    }
    __syncthreads();

    // ================= Phase C: run-based union-find CCL =================
    const unsigned seed = seedSh;
    const int srow = (int)(seed / WW);
    const int scol = (int)(seed % WW);

    // C0: per-row run counts -> roff (temp); zero cmp
    if (tid < HH) {
        u64 st[3]; rowStarts(fgw + tid * WPR, st);
        roff[tid] = (int)__popcll(st[0]) + (int)__popcll(st[1]) + (int)__popcll(st[2]);
    }
    for (int k = tid; k < NWORDS; k += NT) cmp[k] = 0ULL;
    __syncthreads();

    // C1: exclusive scan of per-row counts (wave 0; lane owns rows 3l..3l+2)
    if (wv == 0) {
        const int r0 = 3 * lane;
        const int c0 = roff[r0], c1 = roff[r0 + 1], c2 = roff[r0 + 2];
        int x = c0 + c1 + c2;
        const int mysum = x;
#pragma unroll
        for (int off = 1; off < 64; off <<= 1) {
            int t = __shfl_up(x, off, 64);
            if (lane >= off) x += t;
        }
        const int excl = x - mysum;
        roff[r0] = excl;
        roff[r0 + 1] = excl + c0;
        roff[r0 + 2] = excl + c0 + c1;
        if (lane == 63) roff[HH] = x;
    }
    __syncthreads();

    // C2: extract runs (row per thread), init parent, find seed run
    if (tid < HH) {
        const int r = tid;
        const u64* fr = fgw + r * WPR;
        u64 st[3]; rowStarts(fr, st);
        int idx = roff[r];
#pragma unroll
        for (int w = 0; w < 3; ++w) {
            u64 m = st[w];
            while (m && idx < MAXRUNS) {
                const int s = (w << 6) + (int)(__ffsll(m) - 1);
                m &= m - 1;
                int e = 191;
                int wj = s >> 6;
                const int bj = s & 63;
                u64 inv = ~fr[wj] & (bj == 63 ? 0ULL : (~0ULL << (bj + 1)));
                while (!inv && wj < 2) { ++wj; inv = ~fr[wj]; }
                if (inv) e = (wj << 6) + (int)(__ffsll(inv) - 1) - 1;
                runs[idx] = ((u32)r << 16) | ((u32)s << 8) | (u32)e;
                parent[idx] = (u32)idx;
                if (r == srow && s <= scol && scol <= e) seedRunSh = (u32)idx;
                ++idx;
            }
        }
    }
    __syncthreads();

    // C3: unions — each run links to its max-overlap partner in rows above/below.
    // Runs in a row are disjoint & sorted, so ends increase with starts:
    // the last run with start <= e+1 is the unique overlap candidate.
    {
        const int total = roff[HH] < MAXRUNS ? roff[HH] : MAXRUNS;
        for (int g = tid; g < total; g += NT) {
            const u32 pk = runs[g];
            const int r = (int)(pk >> 16);
            const int s = (int)((pk >> 8) & 0xFFu);
            const int e = (int)(pk & 0xFFu);
            const int hi = (e + 1 > 191) ? 191 : e + 1;
            if (r > 0) {
                u64 st[3]; rowStarts(fgw + (r - 1) * WPR, st);
                const int cnt = rankLE(st, hi);
                if (cnt > 0) {
                    const int idx = roff[r - 1] + cnt - 1;
                    if ((int)(runs[idx] & 0xFFu) >= s - 1)
                        unite((u32)g, (u32)idx, parent);
                }
            }
            if (r < HH - 1) {
                u64 st[3]; rowStarts(fgw + (r + 1) * WPR, st);
                const int cnt = rankLE(st, hi);
                if (cnt > 0) {
                    const int idx = roff[r + 1] + cnt - 1;
                    if ((int)(runs[idx] & 0xFFu) >= s - 1)
                        unite((u32)g, (u32)idx, parent);
                }
            }
        }
    }
    __syncthreads();

    // C4: flatten
    {
        const int total = roff[HH] < MAXRUNS ? roff[HH] : MAXRUNS;
        for (int g = tid; g < total; g += NT)
            parent[g] = repr((u32)g, parent);
    }
    __syncthreads();

    // C5: paint seed component into cmp (parallel over runs, atomicOr)
    {
        const u32 sr = seedRunSh;
        if (sr != 0xFFFFFFFFu) {
            const u32 root = parent[sr];
            const int total = roff[HH] < MAXRUNS ? roff[HH] : MAXRUNS;
            for (int g = tid; g < total; g += NT) {
                if (parent[g] == root) {
                    const u32 pk = runs[g];
                    const int r = (int)(pk >> 16);
                    const int s = (int)((pk >> 8) & 0xFFu);
                    const int e = (int)(pk & 0xFFu);
#pragma unroll
                    for (int w = 0; w < 3; ++w) {
                        const int lo = w << 6;
                        const int a = s - lo, bq = e - lo;
                        if (bq < 0 || a > 63) continue;
                        const int aa = a < 0 ? 0 : a;
                        const int bb = bq > 63 ? 63 : bq;
                        const u64 mm = (bb == 63 ? ~0ULL : ((1ULL << (bb + 1)) - 1ULL))
                                     & (~0ULL << aa);
                        atomicOr(&cmp[r * WPR + w], mm);
                    }
                }
            }
        }
    }
    __syncthreads();

    // ---- Phase D: compact nonempty comp words, split across waves,
    //      software-pipelined preds gather. facc += (cnt/9 + 1) * log(p).
    for (int k = tid; k < NWORDS; k += NT)
        if (cmp[k] != 0ULL) { int idx = atomicAdd(&cntSh, 1); wlist[idx] = (short)k; }
    __syncthreads();
    {
        const int n = cntSh;
        int i = wv;
        int kc = (i < n) ? (int)wlist[i] : -1;
        float pc = 0.0f;
        if (kc >= 0) pc = pp[(kc << 6) + lane];
        while (kc >= 0) {
            const int i2 = i + NW;
            const int k2 = (i2 < n) ? (int)wlist[i2] : -1;
            float p2 = 0.0f;
            if (k2 >= 0) p2 = pp[(k2 << 6) + lane];   // next load in flight
            u64 P0, P1, P2, P3, mid;
            plane9(cmp, kc, P0, P1, P2, P3, mid);
            if ((mid >> lane) & 1ULL) {
                int ct = (int)((P0 >> lane) & 1ULL)
                       | ((int)((P1 >> lane) & 1ULL) << 1)
                       | ((int)((P2 >> lane) & 1ULL) << 2)
                       | ((int)((P3 >> lane) & 1ULL) << 3);
                facc += ((float)ct * (1.0f / 9.0f) + 1.0f) * __logf(pc + 1e-8f);
            }
            i = i2; kc = k2; pc = p2;
        }
    }

    // ---- Reduce ----
#pragma unroll
    for (int off = 32; off > 0; off >>= 1)
        facc += __shfl_xor(facc, off, 64);
    if (lane == 0) wsum[wv] = (double)facc;
    __syncthreads();
    if (tid == 0)
        atomicAdd(acc, wsum[0] + wsum[1] + wsum[2] + wsum[3]);
}

__global__ void finalize_kernel(const double* __restrict__ acc, float* __restrict__ out)
{
    if (threadIdx.x == 0 && blockIdx.x == 0)
        out[0] = (float)(-acc[0] / (double)((long long)BB * SS * NPIX));
}

extern "C" void kernel_launch(void* const* d_in, const int* in_sizes, int n_in,
                              void* d_out, int out_size, void* d_ws, size_t ws_size,
                              hipStream_t stream)
{
    const float* preds   = (const float*)d_in[0];
    const int*   samples = (const int*)d_in[1];
    double* acc = (double*)d_ws;

    hipMemsetAsync(acc, 0, sizeof(double), stream);
    hipLaunchKernelGGL(cc_fused, dim3(NTASK), dim3(NT), SMEM_BYTES, stream,
                       preds, samples, acc);
    hipLaunchKernelGGL(finalize_kernel, dim3(1), dim3(64), 0, stream,
                       acc, (float*)d_out);
}